// Round 1
// baseline (320.407 us; speedup 1.0000x reference)
//
#include <hip/hip_runtime.h>
#include <hip/hip_bf16.h>

// B=4, S=2048, C=1024 attention block, fp32 in/out.
// fp16 MFMA (16x16x32), fp32 accumulate.
// Projection + scores GEMMs: NEW 256x256 8-phase schedule (BK=64, 8 waves,
// 128 KiB LDS dbuf, counted vmcnt(4), raw s_barrier, setprio around MFMA).
// Attn GEMM: previous 128x128 kernel (grid would be only 128 blocks at 256²).
// LDS chunk-XOR swizzle (conflict-free, measured 0 bank conflicts) kept.

typedef _Float16 half8 __attribute__((ext_vector_type(8)));
typedef _Float16 half4 __attribute__((ext_vector_type(4)));
typedef float f32x4 __attribute__((ext_vector_type(4)));

#define AS1(p) ((const __attribute__((address_space(1))) void*)(p))
#define AS3(p) ((__attribute__((address_space(3))) void*)(p))
#define MFMA16(a, b, c) __builtin_amdgcn_mfma_f32_16x16x32_f16(a, b, c, 0, 0, 0)

// ---------------- fp32 -> fp16 convert, 3 tensors per launch ----------------
__global__ __launch_bounds__(256) void cvt3_f32_f16(
    const float* __restrict__ s0, const float* __restrict__ s1,
    const float* __restrict__ s2, _Float16* __restrict__ d0,
    _Float16* __restrict__ d1, _Float16* __restrict__ d2, int n) {
    const float* s = blockIdx.y == 0 ? s0 : blockIdx.y == 1 ? s1 : s2;
    _Float16* d = blockIdx.y == 0 ? d0 : blockIdx.y == 1 ? d1 : d2;
    int i = (blockIdx.x * 256 + threadIdx.x) * 8;
    if (i >= n) return;
    float4 a = *(const float4*)(s + i);
    float4 b = *(const float4*)(s + i + 4);
    half8 h;
    h[0] = (_Float16)a.x; h[1] = (_Float16)a.y; h[2] = (_Float16)a.z; h[3] = (_Float16)a.w;
    h[4] = (_Float16)b.x; h[5] = (_Float16)b.y; h[6] = (_Float16)b.z; h[7] = (_Float16)b.w;
    *(half8*)(d + i) = h;
}

// ---------------- OLD NT GEMM, 128x128 tile, BK=64 (attn stage only) --------
template <int K, int NX_SH, int R, int NYT_SH, bool BIAS, bool F16OUT, bool PROJ3>
__global__ __launch_bounds__(256, 2)
void gemm_nt(const _Float16* __restrict__ A, const _Float16* __restrict__ Bt,
             const float* __restrict__ b0, const float* __restrict__ b1,
             const float* __restrict__ b2, void* __restrict__ Cout,
             _Float16* __restrict__ VtOut, int N, float scale,
             long sA, long sB, long sC) {
    __shared__ _Float16 Asm[128 * 64] __attribute__((aligned(16)));
    __shared__ _Float16 Bsm[128 * 64] __attribute__((aligned(16)));
    const int tid = threadIdx.x;
    const int lane = tid & 63;
    const int wave = tid >> 6;

    const int lin = blockIdx.x;
    const int g = lin & 7;
    const int s = lin >> 3;
    const int xt = s & ((1 << NX_SH) - 1);
    const int row_id = g * R + (s >> NX_SH);
    const int yt = row_id & ((1 << NYT_SH) - 1);
    const int tz = row_id >> NYT_SH;
    const int m0 = yt * 128;
    const int n0 = xt * 128;

    const float* bias = nullptr;
    if constexpr (PROJ3) {
        A += (long)tz * 8388608;
        Bt += (long)tz * 1048576;
        bias = tz == 0 ? b0 : tz == 1 ? b1 : b2;
    } else {
        A += (long)tz * sA;
        Bt += (long)tz * sB;
    }

    const int srow8 = lane >> 3;
    const int sq = ((lane & 7) ^ srow8) << 3;
    const int quad = lane >> 4;
    const int l16 = lane & 15;
    const int wm = (wave >> 1) << 6;
    const int wn = (wave & 1) << 6;
    const int fa0 = (wm + l16) * 64 + (((0 * 4 + quad) ^ (l16 & 7)) << 3);
    const int fa1 = (wm + l16) * 64 + (((1 * 4 + quad) ^ (l16 & 7)) << 3);
    const int fb0 = (wn + l16) * 64 + (((0 * 4 + quad) ^ (l16 & 7)) << 3);
    const int fb1 = (wn + l16) * 64 + (((1 * 4 + quad) ^ (l16 & 7)) << 3);

    f32x4 acc[4][4];
#pragma unroll
    for (int i = 0; i < 4; i++)
#pragma unroll
        for (int j = 0; j < 4; j++)
#pragma unroll
            for (int r = 0; r < 4; r++) acc[i][j][r] = 0.0f;

    const _Float16* Abase = A + (long)m0 * K;
    const _Float16* Bbase = Bt + (long)n0 * K;

    for (int k0 = 0; k0 < K; k0 += 64) {
        __syncthreads();
#pragma unroll
        for (int u = 0; u < 8; ++u) {
            const int t = wave + u * 4;
            if (t < 16) {
                __builtin_amdgcn_global_load_lds(
                    AS1(Abase + (long)(t * 8 + srow8) * K + k0 + sq),
                    AS3(Asm + t * 512), 16, 0, 0);
            } else {
                __builtin_amdgcn_global_load_lds(
                    AS1(Bbase + (long)((t - 16) * 8 + srow8) * K + k0 + sq),
                    AS3(Bsm + (t - 16) * 512), 16, 0, 0);
            }
        }
        __syncthreads();

#pragma unroll
        for (int ks = 0; ks < 2; ++ks) {
            const int ao = ks ? fa1 : fa0;
            const int bo = ks ? fb1 : fb0;
            half8 af[4], bf[4];
#pragma unroll
            for (int i = 0; i < 4; i++) af[i] = *(const half8*)(Asm + ao + i * 1024);
#pragma unroll
            for (int j = 0; j < 4; j++) bf[j] = *(const half8*)(Bsm + bo + j * 1024);
#pragma unroll
            for (int i = 0; i < 4; i++)
#pragma unroll
                for (int j = 0; j < 4; j++)
                    acc[i][j] = MFMA16(af[i], bf[j], acc[i][j]);
        }
    }

    const bool trout = PROJ3 && tz == 2;
#pragma unroll
    for (int i = 0; i < 4; i++) {
        const int row = m0 + wm + i * 16 + quad * 4;
#pragma unroll
        for (int j = 0; j < 4; j++) {
            const int col = n0 + wn + j * 16 + l16;
            const float badd = BIAS ? bias[col] : 0.0f;
            if (trout) {
                const long b = row >> 11;
                const int sl = row & 2047;
                half4 h;
#pragma unroll
                for (int r = 0; r < 4; r++) h[r] = (_Float16)(acc[i][j][r] * scale + badd);
                *(half4*)(VtOut + b * 2097152 + (long)col * 2048 + sl) = h;
            } else if constexpr (PROJ3) {
                _Float16* o = (_Float16*)Cout + (long)tz * 8388608;
#pragma unroll
                for (int r = 0; r < 4; r++)
                    o[(long)(row + r) * N + col] = (_Float16)(acc[i][j][r] * scale + badd);
            } else {
#pragma unroll
                for (int r = 0; r < 4; r++) {
                    float v = acc[i][j][r] * scale + badd;
                    if constexpr (F16OUT)
                        ((_Float16*)Cout + (long)tz * sC)[(long)(row + r) * N + col] = (_Float16)v;
                    else
                        ((float*)Cout + (long)tz * sC)[(long)(row + r) * N + col] = v;
                }
            }
        }
    }
}

// ---------------- NEW: 256x256 8-phase NT GEMM, BK=64, 512 threads ----------
// 8 waves (2Mx4N), wave tile 128x64, acc[8][4] f32x4. LDS [buf][A/B][256][64]
// halves with chunk-XOR swizzle (chunk q of row r at q^(r&7); conflict-free).
// Per K-tile, 4 phases; reads: {A[i0..3]+B[j0..1], B[j2..3], A[i4..7], -}.
// Region-free timing: B of buf c free after phase 1, A free after phase 2.
// Stage slots per phase: {t+1:Ah0 -> buf nb, t+1:Ah1 -> nb, t+2:Bh0 -> c,
// t+2:Bh1 -> c}. vmcnt(4) at end of phase 3 == "all of t+1 landed, t+2's two
// B half-tiles (4 loads/wave) may stay in flight". Raw s_barrier (no vmcnt(0)
// drain), setprio(1) around each 16-MFMA cluster.
template <int K, int NX_SH, int R, int NYT_SH, bool BIAS, bool F16OUT, bool PROJ3>
__global__ __launch_bounds__(512, 2)
void gemm256(const _Float16* __restrict__ A, const _Float16* __restrict__ Bt,
             const float* __restrict__ b0, const float* __restrict__ b1,
             const float* __restrict__ b2, void* __restrict__ Cout,
             _Float16* __restrict__ VtOut, int N, float scale,
             long sA, long sB, long sC) {
    constexpr int NT = K / 64;
    static_assert(NT >= 2, "need >=2 K-tiles");
    __shared__ _Float16 sm[2][2][256 * 64] __attribute__((aligned(16)));  // 128 KiB

    const int tid = threadIdx.x;
    const int lane = tid & 63;
    const int wave = tid >> 6;          // 0..7
    const int wm_i = wave >> 2;         // 0..1
    const int wn_i = wave & 3;          // 0..3

    const int lin = blockIdx.x;
    const int g = lin & 7;
    const int sblk = lin >> 3;
    const int xt = sblk & ((1 << NX_SH) - 1);
    const int row_id = g * R + (sblk >> NX_SH);
    const int yt = row_id & ((1 << NYT_SH) - 1);
    const int tz = row_id >> NYT_SH;
    const int m0 = yt * 256;
    const int n0 = xt * 256;

    const float* bias = nullptr;
    if constexpr (PROJ3) {
        A += (long)tz * 8388608;
        Bt += (long)tz * 1048576;
        bias = tz == 0 ? b0 : tz == 1 ? b1 : b2;
    } else {
        A += (long)tz * sA;
        Bt += (long)tz * sB;
    }
    const _Float16* Abase = A + (long)m0 * K;
    const _Float16* Bbase = Bt + (long)n0 * K;

    // staging per-lane constants (8 lanes cover one 128B row)
    const int srow8 = lane >> 3;
    const int sq = ((lane & 7) ^ srow8) << 3;
    // fragment per-lane constants
    const int quad = lane >> 4;
    const int l16 = lane & 15;
    const int e7 = l16 & 7;
    const int ch0 = (quad ^ e7) << 3;        // ks=0 swizzled chunk (halves)
    const int ch1 = ((4 + quad) ^ e7) << 3;  // ks=1
    const int arow = (wm_i * 128 + l16) * 64;
    const int brow = (wn_i * 64 + l16) * 64;

    f32x4 acc[8][4];
#pragma unroll
    for (int i = 0; i < 8; i++)
#pragma unroll
        for (int j = 0; j < 4; j++)
#pragma unroll
            for (int r = 0; r < 4; r++) acc[i][j][r] = 0.0f;

    // stage one half-tile (128 rows x 64 halves = 16KB): 2 loads/thread
    auto STAGE = [&](int bfi, int ab, int half, int kt) {
        const _Float16* gb = ab ? Bbase : Abase;
#pragma unroll
        for (int u = 0; u < 2; ++u) {
            const int c8 = (u << 3) + wave;                 // 8-row chunk 0..15
            const int r = half * 128 + c8 * 8 + srow8;
            __builtin_amdgcn_global_load_lds(
                AS1(gb + (long)r * K + kt * 64 + sq),
                AS3(&sm[bfi][ab][half * 8192 + c8 * 512]), 16, 0, 0);
        }
    };

    // prologue: tile0 fully + tile1 B-halves (steady-state queue shape)
    STAGE(0, 0, 0, 0);
    STAGE(0, 0, 1, 0);
    STAGE(0, 1, 0, 0);
    STAGE(0, 1, 1, 0);
    STAGE(1, 1, 0, 1);
    STAGE(1, 1, 1, 1);
    asm volatile("s_waitcnt vmcnt(4)" ::: "memory");  // tile0 resident
    __builtin_amdgcn_s_barrier();

    half8 af[4][2], bfr[4][2];
#pragma unroll 2
    for (int t = 0; t < NT; ++t) {
        const int c = t & 1;
        const int nb = c ^ 1;
        const _Float16* sAp = sm[c][0];
        const _Float16* sBp = sm[c][1];

        // ---- phase 0: read A[i0..3]x2ks + B[j0..1]x2ks; stage t+1:Ah0 ----
#pragma unroll
        for (int i = 0; i < 4; ++i) {
            af[i][0] = *(const half8*)(sAp + arow + i * 1024 + ch0);
            af[i][1] = *(const half8*)(sAp + arow + i * 1024 + ch1);
        }
#pragma unroll
        for (int j = 0; j < 2; ++j) {
            bfr[j][0] = *(const half8*)(sBp + brow + j * 1024 + ch0);
            bfr[j][1] = *(const half8*)(sBp + brow + j * 1024 + ch1);
        }
        if (t + 1 < NT) STAGE(nb, 0, 0, t + 1);
        __builtin_amdgcn_s_barrier();
        asm volatile("s_waitcnt lgkmcnt(0)" ::: "memory");
        __builtin_amdgcn_s_setprio(1);
#pragma unroll
        for (int i = 0; i < 4; ++i)
#pragma unroll
            for (int j = 0; j < 2; ++j) {
                acc[i][j] = MFMA16(af[i][0], bfr[j][0], acc[i][j]);
                acc[i][j] = MFMA16(af[i][1], bfr[j][1], acc[i][j]);
            }
        __builtin_amdgcn_s_setprio(0);
        __builtin_amdgcn_s_barrier();

        // ---- phase 1: read B[j2..3]x2ks; stage t+1:Ah1 -------------------
#pragma unroll
        for (int j = 2; j < 4; ++j) {
            bfr[j][0] = *(const half8*)(sBp + brow + j * 1024 + ch0);
            bfr[j][1] = *(const half8*)(sBp + brow + j * 1024 + ch1);
        }
        if (t + 1 < NT) STAGE(nb, 0, 1, t + 1);
        __builtin_amdgcn_s_barrier();
        asm volatile("s_waitcnt lgkmcnt(0)" ::: "memory");
        __builtin_amdgcn_s_setprio(1);
#pragma unroll
        for (int i = 0; i < 4; ++i)
#pragma unroll
            for (int j = 2; j < 4; ++j) {
                acc[i][j] = MFMA16(af[i][0], bfr[j][0], acc[i][j]);
                acc[i][j] = MFMA16(af[i][1], bfr[j][1], acc[i][j]);
            }
        __builtin_amdgcn_s_setprio(0);
        __builtin_amdgcn_s_barrier();
        // all B reads of buf c drained before this point -> B region free

        // ---- phase 2: read A[i4..7]x2ks; stage t+2:Bh0 -> buf c ----------
#pragma unroll
        for (int i = 0; i < 4; ++i) {
            af[i][0] = *(const half8*)(sAp + arow + (i + 4) * 1024 + ch0);
            af[i][1] = *(const half8*)(sAp + arow + (i + 4) * 1024 + ch1);
        }
        if (t + 2 < NT) STAGE(c, 1, 0, t + 2);
        __builtin_amdgcn_s_barrier();
        asm volatile("s_waitcnt lgkmcnt(0)" ::: "memory");
        __builtin_amdgcn_s_setprio(1);
#pragma unroll
        for (int i = 0; i < 4; ++i)
#pragma unroll
            for (int j = 0; j < 2; ++j) {
                acc[i + 4][j] = MFMA16(af[i][0], bfr[j][0], acc[i + 4][j]);
                acc[i + 4][j] = MFMA16(af[i][1], bfr[j][1], acc[i + 4][j]);
            }
        __builtin_amdgcn_s_setprio(0);
        __builtin_amdgcn_s_barrier();
        // all A reads of buf c drained -> A region free

        // ---- phase 3: stage t+2:Bh1 -> buf c; MFMA; counted vmcnt --------
        if (t + 2 < NT) STAGE(c, 1, 1, t + 2);
        __builtin_amdgcn_s_barrier();
        __builtin_amdgcn_s_setprio(1);
#pragma unroll
        for (int i = 0; i < 4; ++i)
#pragma unroll
            for (int j = 2; j < 4; ++j) {
                acc[i + 4][j] = MFMA16(af[i][0], bfr[j][0], acc[i + 4][j]);
                acc[i + 4][j] = MFMA16(af[i][1], bfr[j][1], acc[i + 4][j]);
            }
        __builtin_amdgcn_s_setprio(0);
        if (t + 2 < NT)
            asm volatile("s_waitcnt vmcnt(4)" ::: "memory");  // t+1 resident
        else
            asm volatile("s_waitcnt vmcnt(0)" ::: "memory");  // tail drain
        __builtin_amdgcn_s_barrier();
    }

    // Epilogue: C/D layout col=lane&15, row=quad*4+reg.
    const bool trout = PROJ3 && tz == 2;
#pragma unroll
    for (int i = 0; i < 8; ++i) {
        const int row = m0 + wm_i * 128 + i * 16 + quad * 4;
#pragma unroll
        for (int j = 0; j < 4; ++j) {
            const int col = n0 + wn_i * 64 + j * 16 + l16;
            const float badd = BIAS ? bias[col] : 0.0f;
            if (trout) {
                const long b = row >> 11;
                const int sl = row & 2047;
                half4 h;
#pragma unroll
                for (int r = 0; r < 4; r++) h[r] = (_Float16)(acc[i][j][r] * scale + badd);
                *(half4*)(VtOut + b * 2097152 + (long)col * 2048 + sl) = h;
            } else if constexpr (PROJ3) {
                _Float16* o = (_Float16*)Cout + (long)tz * 8388608;
#pragma unroll
                for (int r = 0; r < 4; r++)
                    o[(long)(row + r) * N + col] = (_Float16)(acc[i][j][r] * scale + badd);
            } else {
#pragma unroll
                for (int r = 0; r < 4; r++) {
                    float v = acc[i][j][r] * scale + badd;
                    if constexpr (F16OUT)
                        ((_Float16*)Cout + (long)tz * sC)[(long)(row + r) * N + col] = (_Float16)v;
                    else
                        ((float*)Cout + (long)tz * sC)[(long)(row + r) * N + col] = v;
                }
            }
        }
    }
}

// ---------------- row softmax: fp16 scores [8192][2048] -> fp16 probs --------
__global__ __launch_bounds__(256) void softmax_f16(const _Float16* __restrict__ S,
                                                   _Float16* __restrict__ P) {
    const long row = blockIdx.x;
    const int t = threadIdx.x;
    const int wave = t >> 6, lane = t & 63;
    half8 h = ((const half8*)(S + row * 2048))[t];
    float v[8];
#pragma unroll
    for (int j = 0; j < 8; j++) v[j] = (float)h[j];
    float m = v[0];
#pragma unroll
    for (int j = 1; j < 8; j++) m = fmaxf(m, v[j]);
#pragma unroll
    for (int off = 32; off > 0; off >>= 1) m = fmaxf(m, __shfl_xor(m, off, 64));
    __shared__ float redm[4], reds[4];
    if (lane == 0) redm[wave] = m;
    __syncthreads();
    m = fmaxf(fmaxf(redm[0], redm[1]), fmaxf(redm[2], redm[3]));
    float sum = 0.0f;
#pragma unroll
    for (int j = 0; j < 8; j++) { v[j] = __expf(v[j] - m); sum += v[j]; }
#pragma unroll
    for (int off = 32; off > 0; off >>= 1) sum += __shfl_xor(sum, off, 64);
    if (lane == 0) reds[wave] = sum;
    __syncthreads();
    sum = (reds[0] + reds[1]) + (reds[2] + reds[3]);
    const float inv = 1.0f / sum;
    half8 o;
#pragma unroll
    for (int j = 0; j < 8; j++) o[j] = (_Float16)(v[j] * inv);
    ((half8*)(P + row * 2048))[t] = o;
}

// ---------------- launch ----------------------------------------------------
extern "C" void kernel_launch(void* const* d_in, const int* in_sizes, int n_in,
                              void* d_out, int out_size, void* d_ws, size_t ws_size,
                              hipStream_t stream) {
    constexpr int B = 4, S = 2048, C = 1024;
    constexpr long XSZ = (long)B * S * C;   // 8388608
    constexpr long WSZ = (long)C * C;       // 1048576

    const float* query = (const float*)d_in[0];
    const float* key   = (const float*)d_in[1];
    const float* value = (const float*)d_in[2];
    const float* Wq = (const float*)d_in[3];
    const float* bq = (const float*)d_in[4];
    const float* Wk = (const float*)d_in[5];
    const float* bk = (const float*)d_in[6];
    const float* Wv = (const float*)d_in[7];
    const float* bv = (const float*)d_in[8];
    float* out = (float*)d_out;
    char* ws = (char*)d_ws;

    _Float16* Xq  = (_Float16*)(ws + 0);
    _Float16* Wqh = (_Float16*)(ws + 3 * XSZ * 2);
    _Float16* scores = (_Float16*)(ws + 0);
    _Float16* Qh  = (_Float16*)(ws + 73400320);
    _Float16* attn = (_Float16*)(ws + 73400320);
    _Float16* Vt  = (_Float16*)(ws + 106954752);
    if (ws_size < 123731968) return;

    // 1) convert inputs + weights to fp16 (contiguous destinations)
    cvt3_f32_f16<<<dim3(XSZ / 2048, 3), 256, 0, stream>>>(
        query, key, value, Xq, Xq + XSZ, Xq + 2 * XSZ, (int)XSZ);
    cvt3_f32_f16<<<dim3(WSZ / 2048, 3), 256, 0, stream>>>(
        Wq, Wk, Wv, Wqh, Wqh + WSZ, Wqh + 2 * WSZ, (int)WSZ);

    // 2) merged projections (8-phase 256²): per tensor M=8192 (32 yt), N=1024
    //    (4 xt). row_ids = 3*32 = 96, R = 96/8 = 12, grid = 8*12*4 = 384.
    gemm256<1024, 2, 12, 5, true, true, true><<<384, 512, 0, stream>>>(
        Xq, Wqh, bq, bk, bv, Qh, Vt, C, 1.0f, 0, 0, 0);

    // 3) scores = Qh @ Kh^T / 32 (8-phase 256²): 8 yt x 8 xt x 4 batches.
    //    row_ids = 32, R = 4, grid = 8*4*8 = 256.
    gemm256<1024, 3, 4, 3, false, true, false><<<256, 512, 0, stream>>>(
        Qh, Qh + XSZ, nullptr, nullptr, nullptr, scores, nullptr, S, 0.03125f,
        (long)S * C, (long)S * C, (long)S * S);

    // 4) row softmax (fp16 in/out)
    softmax_f16<<<B * S, 256, 0, stream>>>(scores, attn);

    // 5) out = attn @ Vt^T (old 128² kernel; 256² would only fill 128 CUs).
    gemm_nt<2048, 3, 8, 4, false, false, false><<<512, 256, 0, stream>>>(
        attn, Vt, nullptr, nullptr, nullptr, out, nullptr, C, 1.0f,
        (long)S * S, (long)C * S, (long)S * C);
}

// Round 2
// 306.274 us; speedup vs baseline: 1.0461x; 1.0461x over previous
//
#include <hip/hip_runtime.h>
#include <hip/hip_bf16.h>

// B=4, S=2048, C=1024 attention block, fp32 in/out.
// fp16 MFMA (16x16x32), fp32 accumulate.
// Projection + scores: 256x256 m201-style schedule, BK=64, 8 waves, 128KiB
// LDS dbuf. Per K-tile 4 quadrant phases (m201 order), 3 barriers/tile,
// counted vmcnt(6) once per tile, sched_barrier(0) after each lgkmcnt(0),
// setprio(1) around MFMA clusters. Attn GEMM: 128x128 m97-style kernel.
// LDS chunk-XOR swizzle (conflict-free, measured 0 bank conflicts).

typedef _Float16 half8 __attribute__((ext_vector_type(8)));
typedef _Float16 half4 __attribute__((ext_vector_type(4)));
typedef float f32x4 __attribute__((ext_vector_type(4)));

#define AS1(p) ((const __attribute__((address_space(1))) void*)(p))
#define AS3(p) ((__attribute__((address_space(3))) void*)(p))
#define MFMA16(a, b, c) __builtin_amdgcn_mfma_f32_16x16x32_f16(a, b, c, 0, 0, 0)

// ---------------- fp32 -> fp16 convert, 3 tensors per launch ----------------
__global__ __launch_bounds__(256) void cvt3_f32_f16(
    const float* __restrict__ s0, const float* __restrict__ s1,
    const float* __restrict__ s2, _Float16* __restrict__ d0,
    _Float16* __restrict__ d1, _Float16* __restrict__ d2, int n) {
    const float* s = blockIdx.y == 0 ? s0 : blockIdx.y == 1 ? s1 : s2;
    _Float16* d = blockIdx.y == 0 ? d0 : blockIdx.y == 1 ? d1 : d2;
    int i = (blockIdx.x * 256 + threadIdx.x) * 8;
    if (i >= n) return;
    float4 a = *(const float4*)(s + i);
    float4 b = *(const float4*)(s + i + 4);
    half8 h;
    h[0] = (_Float16)a.x; h[1] = (_Float16)a.y; h[2] = (_Float16)a.z; h[3] = (_Float16)a.w;
    h[4] = (_Float16)b.x; h[5] = (_Float16)b.y; h[6] = (_Float16)b.z; h[7] = (_Float16)b.w;
    *(half8*)(d + i) = h;
}

// ---------------- 128x128 m97-style NT GEMM (attn stage only) ---------------
template <int K, int NX_SH, int R, int NYT_SH, bool BIAS, bool F16OUT, bool PROJ3>
__global__ __launch_bounds__(256, 2)
void gemm_nt(const _Float16* __restrict__ A, const _Float16* __restrict__ Bt,
             const float* __restrict__ b0, const float* __restrict__ b1,
             const float* __restrict__ b2, void* __restrict__ Cout,
             _Float16* __restrict__ VtOut, int N, float scale,
             long sA, long sB, long sC) {
    __shared__ _Float16 Asm[128 * 64] __attribute__((aligned(16)));
    __shared__ _Float16 Bsm[128 * 64] __attribute__((aligned(16)));
    const int tid = threadIdx.x;
    const int lane = tid & 63;
    const int wave = tid >> 6;

    const int lin = blockIdx.x;
    const int g = lin & 7;
    const int s = lin >> 3;
    const int xt = s & ((1 << NX_SH) - 1);
    const int row_id = g * R + (s >> NX_SH);
    const int yt = row_id & ((1 << NYT_SH) - 1);
    const int tz = row_id >> NYT_SH;
    const int m0 = yt * 128;
    const int n0 = xt * 128;

    const float* bias = nullptr;
    if constexpr (PROJ3) {
        A += (long)tz * 8388608;
        Bt += (long)tz * 1048576;
        bias = tz == 0 ? b0 : tz == 1 ? b1 : b2;
    } else {
        A += (long)tz * sA;
        Bt += (long)tz * sB;
    }

    const int srow8 = lane >> 3;
    const int sq = ((lane & 7) ^ srow8) << 3;
    const int quad = lane >> 4;
    const int l16 = lane & 15;
    const int wm = (wave >> 1) << 6;
    const int wn = (wave & 1) << 6;
    const int fa0 = (wm + l16) * 64 + (((0 * 4 + quad) ^ (l16 & 7)) << 3);
    const int fa1 = (wm + l16) * 64 + (((1 * 4 + quad) ^ (l16 & 7)) << 3);
    const int fb0 = (wn + l16) * 64 + (((0 * 4 + quad) ^ (l16 & 7)) << 3);
    const int fb1 = (wn + l16) * 64 + (((1 * 4 + quad) ^ (l16 & 7)) << 3);

    f32x4 acc[4][4];
#pragma unroll
    for (int i = 0; i < 4; i++)
#pragma unroll
        for (int j = 0; j < 4; j++)
#pragma unroll
            for (int r = 0; r < 4; r++) acc[i][j][r] = 0.0f;

    const _Float16* Abase = A + (long)m0 * K;
    const _Float16* Bbase = Bt + (long)n0 * K;

    for (int k0 = 0; k0 < K; k0 += 64) {
        __syncthreads();
#pragma unroll
        for (int u = 0; u < 8; ++u) {
            const int t = wave + u * 4;
            if (t < 16) {
                __builtin_amdgcn_global_load_lds(
                    AS1(Abase + (long)(t * 8 + srow8) * K + k0 + sq),
                    AS3(Asm + t * 512), 16, 0, 0);
            } else {
                __builtin_amdgcn_global_load_lds(
                    AS1(Bbase + (long)((t - 16) * 8 + srow8) * K + k0 + sq),
                    AS3(Bsm + (t - 16) * 512), 16, 0, 0);
            }
        }
        __syncthreads();

#pragma unroll
        for (int ks = 0; ks < 2; ++ks) {
            const int ao = ks ? fa1 : fa0;
            const int bo = ks ? fb1 : fb0;
            half8 af[4], bf[4];
#pragma unroll
            for (int i = 0; i < 4; i++) af[i] = *(const half8*)(Asm + ao + i * 1024);
#pragma unroll
            for (int j = 0; j < 4; j++) bf[j] = *(const half8*)(Bsm + bo + j * 1024);
#pragma unroll
            for (int i = 0; i < 4; i++)
#pragma unroll
                for (int j = 0; j < 4; j++)
                    acc[i][j] = MFMA16(af[i], bf[j], acc[i][j]);
        }
    }

    const bool trout = PROJ3 && tz == 2;
#pragma unroll
    for (int i = 0; i < 4; i++) {
        const int row = m0 + wm + i * 16 + quad * 4;
#pragma unroll
        for (int j = 0; j < 4; j++) {
            const int col = n0 + wn + j * 16 + l16;
            const float badd = BIAS ? bias[col] : 0.0f;
            if (trout) {
                const long b = row >> 11;
                const int sl = row & 2047;
                half4 h;
#pragma unroll
                for (int r = 0; r < 4; r++) h[r] = (_Float16)(acc[i][j][r] * scale + badd);
                *(half4*)(VtOut + b * 2097152 + (long)col * 2048 + sl) = h;
            } else if constexpr (PROJ3) {
                _Float16* o = (_Float16*)Cout + (long)tz * 8388608;
#pragma unroll
                for (int r = 0; r < 4; r++)
                    o[(long)(row + r) * N + col] = (_Float16)(acc[i][j][r] * scale + badd);
            } else {
#pragma unroll
                for (int r = 0; r < 4; r++) {
                    float v = acc[i][j][r] * scale + badd;
                    if constexpr (F16OUT)
                        ((_Float16*)Cout + (long)tz * sC)[(long)(row + r) * N + col] = (_Float16)v;
                    else
                        ((float*)Cout + (long)tz * sC)[(long)(row + r) * N + col] = v;
                }
            }
        }
    }
}

// ---------------- 256x256 m201-style NT GEMM, BK=64, 512 threads ------------
// 8 waves (2Mx4N), wave tile 128x64, acc[8][4] f32x4 (AGPR).
// Quadrant order per K-tile t (buf c): q0: read af[0..3]+bf[0..1] (12), MFMA
// (i0-3 x j0-1); q1: read af[4..7] (8), MFMA (i4-7 x j0-1), BAR; q2: read
// bf[2..3] (4), MFMA (i0-3 x j2-3), BAR; q3: MFMA (i4-7 x j2-3), vmcnt, BAR.
// A[c] fully serviced by q1-close, B[c] by q2-close -> stage slots:
// q0: Bh1(t+1)->nb; q2: Ah0+Ah1(t+2)->c; q3: Bh0(t+2)->c. Steady in-flight at
// q3 wait = {Ah(t+2)x2, Bh0(t+2)} = 6 loads -> vmcnt(6) (3 half-tiles, issued
// 3-6.5 phases before the wait). sched_barrier(0) after each lgkmcnt(0)
// (rule #18: stop MFMA hoisting past inline-asm waitcnt).
template <int K, int NX_SH, int R, int NYT_SH, bool BIAS, bool F16OUT, bool PROJ3>
__global__ __launch_bounds__(512, 2)
void gemm256(const _Float16* __restrict__ A, const _Float16* __restrict__ Bt,
             const float* __restrict__ b0, const float* __restrict__ b1,
             const float* __restrict__ b2, void* __restrict__ Cout,
             _Float16* __restrict__ VtOut, int N, float scale,
             long sA, long sB, long sC) {
    constexpr int NT = K / 64;
    static_assert(NT >= 3, "prologue needs >=3 K-tiles");
    __shared__ _Float16 sm[2][2][256 * 64] __attribute__((aligned(16)));  // 128 KiB

    const int tid = threadIdx.x;
    const int lane = tid & 63;
    const int wave = tid >> 6;          // 0..7
    const int wm_i = wave >> 2;         // 0..1
    const int wn_i = wave & 3;          // 0..3

    const int lin = blockIdx.x;
    const int g = lin & 7;
    const int sblk = lin >> 3;
    const int xt = sblk & ((1 << NX_SH) - 1);
    const int row_id = g * R + (sblk >> NX_SH);
    const int yt = row_id & ((1 << NYT_SH) - 1);
    const int tz = row_id >> NYT_SH;
    const int m0 = yt * 256;
    const int n0 = xt * 256;

    const float* bias = nullptr;
    if constexpr (PROJ3) {
        A += (long)tz * 8388608;
        Bt += (long)tz * 1048576;
        bias = tz == 0 ? b0 : tz == 1 ? b1 : b2;
    } else {
        A += (long)tz * sA;
        Bt += (long)tz * sB;
    }
    const _Float16* Abase = A + (long)m0 * K;
    const _Float16* Bbase = Bt + (long)n0 * K;

    // staging per-lane constants (8 lanes cover one 128B row)
    const int srow8 = lane >> 3;
    const int sq = ((lane & 7) ^ srow8) << 3;
    // fragment per-lane constants
    const int quad = lane >> 4;
    const int l16 = lane & 15;
    const int e7 = l16 & 7;
    const int ch0 = (quad ^ e7) << 3;        // ks=0 swizzled chunk (halves)
    const int ch1 = ((4 + quad) ^ e7) << 3;  // ks=1
    const int arow = (wm_i * 128 + l16) * 64;
    const int brow = (wn_i * 64 + l16) * 64;

    f32x4 acc[8][4];
#pragma unroll
    for (int i = 0; i < 8; i++)
#pragma unroll
        for (int j = 0; j < 4; j++)
#pragma unroll
            for (int r = 0; r < 4; r++) acc[i][j][r] = 0.0f;

    // stage one half-tile (128 rows x 64 halves = 16KB): 2 loads/thread
    auto STAGE = [&](int bfi, int ab, int half, int kt) {
        const _Float16* gb = ab ? Bbase : Abase;
#pragma unroll
        for (int u = 0; u < 2; ++u) {
            const int c8 = (u << 3) + wave;                 // 8-row chunk 0..15
            const int r = half * 128 + c8 * 8 + srow8;
            __builtin_amdgcn_global_load_lds(
                AS1(gb + (long)r * K + kt * 64 + sq),
                AS3(&sm[bfi][ab][half * 8192 + c8 * 512]), 16, 0, 0);
        }
    };

    // prologue: tile0 fully (8 loads), tile1 Ah0,Ah1,Bh0 (6 loads).
    // vmcnt(6) drains tile0; steady invariant {Ah(t+1)x2, Bh0(t+1)} in flight.
    STAGE(0, 0, 0, 0);
    STAGE(0, 0, 1, 0);
    STAGE(0, 1, 0, 0);
    STAGE(0, 1, 1, 0);
    STAGE(1, 0, 0, 1);
    STAGE(1, 0, 1, 1);
    STAGE(1, 1, 0, 1);
    asm volatile("s_waitcnt vmcnt(6)" ::: "memory");
    __builtin_amdgcn_s_barrier();

    half8 af[8][2], bfr[2][2];
#pragma unroll 2
    for (int t = 0; t < NT; ++t) {
        const int c = t & 1;
        const int nb = c ^ 1;
        const _Float16* sAp = sm[c][0];
        const _Float16* sBp = sm[c][1];

        // ---- q0: read af[0..3]x2 + bf[0..1]x2 (12); stage Bh1(t+1)->nb ----
#pragma unroll
        for (int i = 0; i < 4; ++i) {
            af[i][0] = *(const half8*)(sAp + arow + i * 1024 + ch0);
            af[i][1] = *(const half8*)(sAp + arow + i * 1024 + ch1);
        }
#pragma unroll
        for (int j = 0; j < 2; ++j) {
            bfr[j][0] = *(const half8*)(sBp + brow + j * 1024 + ch0);
            bfr[j][1] = *(const half8*)(sBp + brow + j * 1024 + ch1);
        }
        if (t + 1 < NT) STAGE(nb, 1, 1, t + 1);
        asm volatile("s_waitcnt lgkmcnt(0)" ::: "memory");
        __builtin_amdgcn_sched_barrier(0);
        __builtin_amdgcn_s_setprio(1);
#pragma unroll
        for (int i = 0; i < 4; ++i)
#pragma unroll
            for (int j = 0; j < 2; ++j) {
                acc[i][j] = MFMA16(af[i][0], bfr[j][0], acc[i][j]);
                acc[i][j] = MFMA16(af[i][1], bfr[j][1], acc[i][j]);
            }
        __builtin_amdgcn_s_setprio(0);
        // no barrier: q0 MFMA may overlap q1 reads across waves

        // ---- q1: read af[4..7]x2 (8); MFMA (i4-7 x j0-1); BARRIER ---------
#pragma unroll
        for (int i = 4; i < 8; ++i) {
            af[i][0] = *(const half8*)(sAp + arow + i * 1024 + ch0);
            af[i][1] = *(const half8*)(sAp + arow + i * 1024 + ch1);
        }
        asm volatile("s_waitcnt lgkmcnt(0)" ::: "memory");
        __builtin_amdgcn_sched_barrier(0);
        __builtin_amdgcn_s_setprio(1);
#pragma unroll
        for (int i = 4; i < 8; ++i)
#pragma unroll
            for (int j = 0; j < 2; ++j) {
                acc[i][j] = MFMA16(af[i][0], bfr[j][0], acc[i][j]);
                acc[i][j] = MFMA16(af[i][1], bfr[j][1], acc[i][j]);
            }
        __builtin_amdgcn_s_setprio(0);
        __builtin_amdgcn_s_barrier();  // A[c] fully serviced by all waves

        // ---- q2: read bf[2..3]x2 (4, reuse bfr); stage Ah0+Ah1(t+2)->c ----
#pragma unroll
        for (int j = 0; j < 2; ++j) {
            bfr[j][0] = *(const half8*)(sBp + brow + (j + 2) * 1024 + ch0);
            bfr[j][1] = *(const half8*)(sBp + brow + (j + 2) * 1024 + ch1);
        }
        if (t + 2 < NT) {
            STAGE(c, 0, 0, t + 2);
            STAGE(c, 0, 1, t + 2);
        }
        asm volatile("s_waitcnt lgkmcnt(0)" ::: "memory");
        __builtin_amdgcn_sched_barrier(0);
        __builtin_amdgcn_s_setprio(1);
#pragma unroll
        for (int i = 0; i < 4; ++i)
#pragma unroll
            for (int j = 0; j < 2; ++j) {
                acc[i][j + 2] = MFMA16(af[i][0], bfr[j][0], acc[i][j + 2]);
                acc[i][j + 2] = MFMA16(af[i][1], bfr[j][1], acc[i][j + 2]);
            }
        __builtin_amdgcn_s_setprio(0);
        __builtin_amdgcn_s_barrier();  // B[c] fully serviced by all waves

        // ---- q3: stage Bh0(t+2)->c; MFMA (i4-7 x j2-3); vmcnt; BARRIER ----
        if (t + 2 < NT) STAGE(c, 1, 0, t + 2);
        __builtin_amdgcn_s_setprio(1);
#pragma unroll
        for (int i = 4; i < 8; ++i)
#pragma unroll
            for (int j = 0; j < 2; ++j) {
                acc[i][j + 2] = MFMA16(af[i][0], bfr[j][0], acc[i][j + 2]);
                acc[i][j + 2] = MFMA16(af[i][1], bfr[j][1], acc[i][j + 2]);
            }
        __builtin_amdgcn_s_setprio(0);
        if (t + 2 < NT)
            asm volatile("s_waitcnt vmcnt(6)" ::: "memory");  // t+1 resident
        else if (t + 1 < NT)
            asm volatile("s_waitcnt vmcnt(0)" ::: "memory");  // tail drain
        __builtin_amdgcn_s_barrier();
    }

    // Epilogue: C/D layout col=lane&15, row=quad*4+reg.
    const bool trout = PROJ3 && tz == 2;
#pragma unroll
    for (int i = 0; i < 8; ++i) {
        const int row = m0 + wm_i * 128 + i * 16 + quad * 4;
#pragma unroll
        for (int j = 0; j < 4; ++j) {
            const int col = n0 + wn_i * 64 + j * 16 + l16;
            const float badd = BIAS ? bias[col] : 0.0f;
            if (trout) {
                const long b = row >> 11;
                const int sl = row & 2047;
                half4 h;
#pragma unroll
                for (int r = 0; r < 4; r++) h[r] = (_Float16)(acc[i][j][r] * scale + badd);
                *(half4*)(VtOut + b * 2097152 + (long)col * 2048 + sl) = h;
            } else if constexpr (PROJ3) {
                _Float16* o = (_Float16*)Cout + (long)tz * 8388608;
#pragma unroll
                for (int r = 0; r < 4; r++)
                    o[(long)(row + r) * N + col] = (_Float16)(acc[i][j][r] * scale + badd);
            } else {
#pragma unroll
                for (int r = 0; r < 4; r++) {
                    float v = acc[i][j][r] * scale + badd;
                    if constexpr (F16OUT)
                        ((_Float16*)Cout + (long)tz * sC)[(long)(row + r) * N + col] = (_Float16)v;
                    else
                        ((float*)Cout + (long)tz * sC)[(long)(row + r) * N + col] = v;
                }
            }
        }
    }
}

// ---------------- row softmax: fp16 scores [8192][2048] -> fp16 probs --------
__global__ __launch_bounds__(256) void softmax_f16(const _Float16* __restrict__ S,
                                                   _Float16* __restrict__ P) {
    const long row = blockIdx.x;
    const int t = threadIdx.x;
    const int wave = t >> 6, lane = t & 63;
    half8 h = ((const half8*)(S + row * 2048))[t];
    float v[8];
#pragma unroll
    for (int j = 0; j < 8; j++) v[j] = (float)h[j];
    float m = v[0];
#pragma unroll
    for (int j = 1; j < 8; j++) m = fmaxf(m, v[j]);
#pragma unroll
    for (int off = 32; off > 0; off >>= 1) m = fmaxf(m, __shfl_xor(m, off, 64));
    __shared__ float redm[4], reds[4];
    if (lane == 0) redm[wave] = m;
    __syncthreads();
    m = fmaxf(fmaxf(redm[0], redm[1]), fmaxf(redm[2], redm[3]));
    float sum = 0.0f;
#pragma unroll
    for (int j = 0; j < 8; j++) { v[j] = __expf(v[j] - m); sum += v[j]; }
#pragma unroll
    for (int off = 32; off > 0; off >>= 1) sum += __shfl_xor(sum, off, 64);
    if (lane == 0) reds[wave] = sum;
    __syncthreads();
    sum = (reds[0] + reds[1]) + (reds[2] + reds[3]);
    const float inv = 1.0f / sum;
    half8 o;
#pragma unroll
    for (int j = 0; j < 8; j++) o[j] = (_Float16)(v[j] * inv);
    ((half8*)(P + row * 2048))[t] = o;
}

// ---------------- launch ----------------------------------------------------
extern "C" void kernel_launch(void* const* d_in, const int* in_sizes, int n_in,
                              void* d_out, int out_size, void* d_ws, size_t ws_size,
                              hipStream_t stream) {
    constexpr int B = 4, S = 2048, C = 1024;
    constexpr long XSZ = (long)B * S * C;   // 8388608
    constexpr long WSZ = (long)C * C;       // 1048576

    const float* query = (const float*)d_in[0];
    const float* key   = (const float*)d_in[1];
    const float* value = (const float*)d_in[2];
    const float* Wq = (const float*)d_in[3];
    const float* bq = (const float*)d_in[4];
    const float* Wk = (const float*)d_in[5];
    const float* bk = (const float*)d_in[6];
    const float* Wv = (const float*)d_in[7];
    const float* bv = (const float*)d_in[8];
    float* out = (float*)d_out;
    char* ws = (char*)d_ws;

    _Float16* Xq  = (_Float16*)(ws + 0);
    _Float16* Wqh = (_Float16*)(ws + 3 * XSZ * 2);
    _Float16* scores = (_Float16*)(ws + 0);
    _Float16* Qh  = (_Float16*)(ws + 73400320);
    _Float16* attn = (_Float16*)(ws + 73400320);
    _Float16* Vt  = (_Float16*)(ws + 106954752);
    if (ws_size < 123731968) return;

    // 1) convert inputs + weights to fp16 (contiguous destinations)
    cvt3_f32_f16<<<dim3(XSZ / 2048, 3), 256, 0, stream>>>(
        query, key, value, Xq, Xq + XSZ, Xq + 2 * XSZ, (int)XSZ);
    cvt3_f32_f16<<<dim3(WSZ / 2048, 3), 256, 0, stream>>>(
        Wq, Wk, Wv, Wqh, Wqh + WSZ, Wqh + 2 * WSZ, (int)WSZ);

    // 2) merged projections (256² m201-style): per tensor M=8192 (32 yt),
    //    N=1024 (4 xt). row_ids = 96, R = 12, grid = 8*12*4 = 384.
    gemm256<1024, 2, 12, 5, true, true, true><<<384, 512, 0, stream>>>(
        Xq, Wqh, bq, bk, bv, Qh, Vt, C, 1.0f, 0, 0, 0);

    // 3) scores = Qh @ Kh^T / 32 (256²): 8 yt x 8 xt x 4 batches, grid 256.
    gemm256<1024, 3, 4, 3, false, true, false><<<256, 512, 0, stream>>>(
        Qh, Qh + XSZ, nullptr, nullptr, nullptr, scores, nullptr, S, 0.03125f,
        (long)S * C, (long)S * C, (long)S * S);

    // 4) row softmax (fp16 in/out)
    softmax_f16<<<B * S, 256, 0, stream>>>(scores, attn);

    // 5) out = attn @ Vt^T (128² kernel; 256² would only fill 128 CUs).
    gemm_nt<2048, 3, 8, 4, false, false, false><<<512, 256, 0, stream>>>(
        attn, Vt, nullptr, nullptr, nullptr, out, nullptr, C, 1.0f,
        (long)S * S, (long)C * S, (long)S * C);
}

// Round 3
// 298.179 us; speedup vs baseline: 1.0745x; 1.0271x over previous
//
#include <hip/hip_runtime.h>
#include <hip/hip_bf16.h>

// B=4, S=2048, C=1024 attention block, fp32 in/out.
// fp16 MFMA (16x16x32), fp32 accumulate. PROVEN 128x128 2-phase structure,
// now with BK=128 (64 KB LDS, still 2 blocks/CU): half the barrier-drain
// events vs BK=64. 16-chunk row swizzle: logical chunk q of row r stored at
// physical q^(r&15); staging source pre-inverse-swizzled, LDS dest linear.
// XCD-aware block remap. Merged single cvt dispatch for inputs+weights.

typedef _Float16 half8 __attribute__((ext_vector_type(8)));
typedef _Float16 half4 __attribute__((ext_vector_type(4)));
typedef float f32x4 __attribute__((ext_vector_type(4)));

#define AS1(p) ((const __attribute__((address_space(1))) void*)(p))
#define AS3(p) ((__attribute__((address_space(3))) void*)(p))
#define MFMA16(a, b, c) __builtin_amdgcn_mfma_f32_16x16x32_f16(a, b, c, 0, 0, 0)

// ---------------- fp32 -> fp16 convert, 6 tensors, ONE launch ---------------
// blocks 0..12287: inputs (3 x 4096 blocks of 2048 elems, XSZ=8388608)
// blocks 12288..13823: weights (3 x 512 blocks, WSZ=1048576)
__global__ __launch_bounds__(256) void cvt6_f32_f16(
    const float* __restrict__ q, const float* __restrict__ k,
    const float* __restrict__ v, const float* __restrict__ wq,
    const float* __restrict__ wk, const float* __restrict__ wv,
    _Float16* __restrict__ Xq, _Float16* __restrict__ Wqh) {
    constexpr long XSZ = 8388608, WSZ = 1048576;
    const int b = blockIdx.x;
    const float* s;
    _Float16* d;
    long i;
    if (b < 12288) {
        const int tz = b >> 12;
        s = tz == 0 ? q : tz == 1 ? k : v;
        d = Xq + (long)tz * XSZ;
        i = (long)(b & 4095) * 2048 + threadIdx.x * 8;
    } else {
        const int b2 = b - 12288;
        const int tz = b2 >> 9;
        s = tz == 0 ? wq : tz == 1 ? wk : wv;
        d = Wqh + (long)tz * WSZ;
        i = (long)(b2 & 511) * 2048 + threadIdx.x * 8;
    }
    float4 a = *(const float4*)(s + i);
    float4 c = *(const float4*)(s + i + 4);
    half8 h;
    h[0] = (_Float16)a.x; h[1] = (_Float16)a.y; h[2] = (_Float16)a.z; h[3] = (_Float16)a.w;
    h[4] = (_Float16)c.x; h[5] = (_Float16)c.y; h[6] = (_Float16)c.z; h[7] = (_Float16)c.w;
    *(half8*)(d + i) = h;
}

// ---------------- NT GEMM, 128x128 tile, BK=128 -----------------------------
// C[m,n] = scale*sum_k A[m,k]*Bt[n,k] (+bias[n]).
// LDS rows = 128 halves (256 B = 16 x 16B chunks). Swizzle: logical chunk q
// of row r at physical q^(r&15). Staging: 64 lanes cover a 4-row slab
// (lane>>4 = row-in-slab, lane&15 = physical chunk); source logical chunk =
// (lane&15)^(r&15). 64 slabs/iter (A:0-31, B:32-63), 16 loads/thread.
// Fragments: ks in 0..3, logical chunk ks*4+quad, physical ^(l16) since
// fragment rows == l16 mod 16. 4 ks-substeps x 16 MFMA per iteration.
// Block remap: xcd = lin&7; each XCD owns R contiguous row_ids x all NX.
// PROJ3: row_id high bits select tensor tz in {0,1,2}=Q,K,V; V writes C^T.
template <int K, int NX_SH, int R, int NYT_SH, bool BIAS, bool F16OUT, bool PROJ3>
__global__ __launch_bounds__(256, 2)
void gemm_nt(const _Float16* __restrict__ A, const _Float16* __restrict__ Bt,
             const float* __restrict__ b0, const float* __restrict__ b1,
             const float* __restrict__ b2, void* __restrict__ Cout,
             _Float16* __restrict__ VtOut, int N, float scale,
             long sA, long sB, long sC) {
    __shared__ _Float16 Asm[128 * 128] __attribute__((aligned(16)));
    __shared__ _Float16 Bsm[128 * 128] __attribute__((aligned(16)));
    const int tid = threadIdx.x;
    const int lane = tid & 63;
    const int wave = tid >> 6;

    const int lin = blockIdx.x;
    const int g = lin & 7;
    const int s = lin >> 3;
    const int xt = s & ((1 << NX_SH) - 1);
    const int row_id = g * R + (s >> NX_SH);
    const int yt = row_id & ((1 << NYT_SH) - 1);
    const int tz = row_id >> NYT_SH;     // PROJ3: tensor id; else: batch id
    const int m0 = yt * 128;
    const int n0 = xt * 128;

    const float* bias = nullptr;
    if constexpr (PROJ3) {
        A += (long)tz * 8388608;         // Xq,Xk,Xv contiguous
        Bt += (long)tz * 1048576;        // Wqh,Wkh,Wvh contiguous
        bias = tz == 0 ? b0 : tz == 1 ? b1 : b2;
    } else {
        A += (long)tz * sA;
        Bt += (long)tz * sB;
    }

    // staging per-lane constants
    const int rin = lane >> 4;           // row within 4-row slab, 0..3
    const int pch = lane & 15;           // physical chunk 0..15
    // fragment per-lane constants
    const int quad = lane >> 4;
    const int l16 = lane & 15;
    const int wm = (wave >> 1) << 6;
    const int wn = (wave & 1) << 6;
    const int fa_base = (wm + l16) * 128;
    const int fb_base = (wn + l16) * 128;
    int ch[4];
#pragma unroll
    for (int ks = 0; ks < 4; ++ks) ch[ks] = (((ks * 4 + quad) ^ l16) << 3);

    f32x4 acc[4][4];
#pragma unroll
    for (int i = 0; i < 4; i++)
#pragma unroll
        for (int j = 0; j < 4; j++)
#pragma unroll
            for (int r = 0; r < 4; r++) acc[i][j][r] = 0.0f;

    const _Float16* Abase = A + (long)m0 * K;
    const _Float16* Bbase = Bt + (long)n0 * K;

    for (int k0 = 0; k0 < K; k0 += 128) {
        __syncthreads();  // previous iteration's LDS reads complete
#pragma unroll
        for (int u = 0; u < 16; ++u) {
            const int t = wave + u * 4;            // slab 0..63 (A:0-31, B:32-63)
            const int sl = t & 31;
            const int r = sl * 4 + rin;            // row 0..127
            // logical chunk = pch ^ (r & 15); r&15 = (sl&3)*4 + rin
            const int lq = (pch ^ (((sl & 3) << 2) + rin)) << 3;  // halves
            if (t < 32) {
                __builtin_amdgcn_global_load_lds(
                    AS1(Abase + (long)r * K + k0 + lq),
                    AS3(Asm + sl * 512), 16, 0, 0);
            } else {
                __builtin_amdgcn_global_load_lds(
                    AS1(Bbase + (long)r * K + k0 + lq),
                    AS3(Bsm + sl * 512), 16, 0, 0);
            }
        }
        __syncthreads();  // staging drained

#pragma unroll
        for (int ks = 0; ks < 4; ++ks) {
            half8 af[4], bf[4];
#pragma unroll
            for (int i = 0; i < 4; i++) af[i] = *(const half8*)(Asm + fa_base + i * 2048 + ch[ks]);
#pragma unroll
            for (int j = 0; j < 4; j++) bf[j] = *(const half8*)(Bsm + fb_base + j * 2048 + ch[ks]);
#pragma unroll
            for (int i = 0; i < 4; i++)
#pragma unroll
                for (int j = 0; j < 4; j++)
                    acc[i][j] = MFMA16(af[i], bf[j], acc[i][j]);
        }
    }

    // Epilogue: C/D layout col=lane&15, row=quad*4+reg (m89/m121-128 verified).
    const bool trout = PROJ3 && tz == 2;
#pragma unroll
    for (int i = 0; i < 4; i++) {
        const int row = m0 + wm + i * 16 + quad * 4;
#pragma unroll
        for (int j = 0; j < 4; j++) {
            const int col = n0 + wn + j * 16 + l16;
            const float badd = BIAS ? bias[col] : 0.0f;
            if (trout) {
                // Vt[b][col][row&2047]; 4 consecutive s-elems per lane (8B store)
                const long b = row >> 11;
                const int sl = row & 2047;
                half4 h;
#pragma unroll
                for (int r = 0; r < 4; r++) h[r] = (_Float16)(acc[i][j][r] * scale + badd);
                *(half4*)(VtOut + b * 2097152 + (long)col * 2048 + sl) = h;
            } else if constexpr (PROJ3) {
                _Float16* o = (_Float16*)Cout + (long)tz * 8388608;
#pragma unroll
                for (int r = 0; r < 4; r++)
                    o[(long)(row + r) * N + col] = (_Float16)(acc[i][j][r] * scale + badd);
            } else {
#pragma unroll
                for (int r = 0; r < 4; r++) {
                    float v = acc[i][j][r] * scale + badd;
                    if constexpr (F16OUT)
                        ((_Float16*)Cout + (long)tz * sC)[(long)(row + r) * N + col] = (_Float16)v;
                    else
                        ((float*)Cout + (long)tz * sC)[(long)(row + r) * N + col] = v;
                }
            }
        }
    }
}

// ---------------- row softmax: fp16 scores [8192][2048] -> fp16 probs --------
__global__ __launch_bounds__(256) void softmax_f16(const _Float16* __restrict__ S,
                                                   _Float16* __restrict__ P) {
    const long row = blockIdx.x;
    const int t = threadIdx.x;
    const int wave = t >> 6, lane = t & 63;
    half8 h = ((const half8*)(S + row * 2048))[t];
    float v[8];
#pragma unroll
    for (int j = 0; j < 8; j++) v[j] = (float)h[j];
    float m = v[0];
#pragma unroll
    for (int j = 1; j < 8; j++) m = fmaxf(m, v[j]);
#pragma unroll
    for (int off = 32; off > 0; off >>= 1) m = fmaxf(m, __shfl_xor(m, off, 64));
    __shared__ float redm[4], reds[4];
    if (lane == 0) redm[wave] = m;
    __syncthreads();
    m = fmaxf(fmaxf(redm[0], redm[1]), fmaxf(redm[2], redm[3]));
    float sum = 0.0f;
#pragma unroll
    for (int j = 0; j < 8; j++) { v[j] = __expf(v[j] - m); sum += v[j]; }
#pragma unroll
    for (int off = 32; off > 0; off >>= 1) sum += __shfl_xor(sum, off, 64);
    if (lane == 0) reds[wave] = sum;
    __syncthreads();
    sum = (reds[0] + reds[1]) + (reds[2] + reds[3]);
    const float inv = 1.0f / sum;
    half8 o;
#pragma unroll
    for (int j = 0; j < 8; j++) o[j] = (_Float16)(v[j] * inv);
    ((half8*)(P + row * 2048))[t] = o;
}

// ---------------- launch ----------------------------------------------------
extern "C" void kernel_launch(void* const* d_in, const int* in_sizes, int n_in,
                              void* d_out, int out_size, void* d_ws, size_t ws_size,
                              hipStream_t stream) {
    constexpr int B = 4, S = 2048, C = 1024;
    constexpr long XSZ = (long)B * S * C;   // 8388608
    constexpr long WSZ = (long)C * C;       // 1048576

    const float* query = (const float*)d_in[0];
    const float* key   = (const float*)d_in[1];
    const float* value = (const float*)d_in[2];
    const float* Wq = (const float*)d_in[3];
    const float* bq = (const float*)d_in[4];
    const float* Wk = (const float*)d_in[5];
    const float* bk = (const float*)d_in[6];
    const float* Wv = (const float*)d_in[7];
    const float* bv = (const float*)d_in[8];
    float* out = (float*)d_out;
    char* ws = (char*)d_ws;

    // Workspace (bytes): [0,50331648) Xq,Xk,Xv contiguous; [50331648,56623104)
    // Wqh,Wkh,Wvh contiguous; region reused for fp16 scores after projections.
    // [73400320) Qh,Kh contiguous (reused for attn). [106954752) Vt.
    _Float16* Xq  = (_Float16*)(ws + 0);
    _Float16* Wqh = (_Float16*)(ws + 3 * XSZ * 2);
    _Float16* scores = (_Float16*)(ws + 0);
    _Float16* Qh  = (_Float16*)(ws + 73400320);
    _Float16* attn = (_Float16*)(ws + 73400320);
    _Float16* Vt  = (_Float16*)(ws + 106954752);
    if (ws_size < 123731968) return;

    // 1) convert inputs + weights to fp16 (one launch, contiguous dests)
    cvt6_f32_f16<<<13824, 256, 0, stream>>>(
        query, key, value, Wq, Wk, Wv, Xq, Wqh);

    // 2) merged projections: per tensor M=8192 (64 y), N=1024 (8 x), K=1024.
    //    row_ids = 3*64=192, grid = 8*192 = 1536 (3.0 rounds @ 2/CU), R = 24.
    gemm_nt<1024, 3, 24, 6, true, true, true><<<1536, 256, 0, stream>>>(
        Xq, Wqh, bq, bk, bv, Qh, Vt, C, 1.0f, 0, 0, 0);

    // 3) scores = Qh @ Kh^T / 32, fp16 out. 16 x, 16 y, z=4 -> grid 1024 (2.0
    //    rounds), R=8.
    gemm_nt<1024, 4, 8, 4, false, true, false><<<1024, 256, 0, stream>>>(
        Qh, Qh + XSZ, nullptr, nullptr, nullptr, scores, nullptr, S, 0.03125f,
        (long)S * C, (long)S * C, (long)S * S);

    // 4) row softmax (fp16 in/out)
    softmax_f16<<<B * S, 256, 0, stream>>>(scores, attn);

    // 5) out = attn @ Vt^T. 8 x, 16 y, z=4 -> grid 512 (1.0 round). fp32 out.
    gemm_nt<2048, 3, 8, 4, false, false, false><<<512, 256, 0, stream>>>(
        attn, Vt, nullptr, nullptr, nullptr, out, nullptr, C, 1.0f,
        (long)S * S, (long)C * S, (long)S * C);
}